// Round 9
// baseline (183.771 us; speedup 1.0000x reference)
//
#include <hip/hip_runtime.h>
#include <math.h>

#define Bn 4
#define Cn 64
#define On 64
#define Hn 128
#define Wn 128
#define Kn 9
#define HWn (Hn*Wn)
#define ZROW 16384            // per-batch zero row index
#define XBSTRIDE (16385*64)   // per-batch stride (16384 rows + 1 zero row)

typedef _Float16 v8h __attribute__((ext_vector_type(8)));
typedef float v4f __attribute__((ext_vector_type(4)));

__device__ inline unsigned short f2h(float f) {
  _Float16 h = (_Float16)f;
  return __builtin_bit_cast(unsigned short, h);
}
__device__ inline _Float16 u2h(unsigned v) {
  return __builtin_bit_cast(_Float16, (unsigned short)(v & 0xffff));
}
__device__ inline v8h sp8(_Float16 x) { v8h v = {x,x,x,x,x,x,x,x}; return v; }

// global -> LDS direct DMA, 16B per lane, LDS dest = uniform base + lane*16
__device__ inline void gld_lds16(const void* g, void* s) {
  __builtin_amdgcn_global_load_lds(
      (const __attribute__((address_space(1))) unsigned int*)g,
      (__attribute__((address_space(3))) unsigned int*)s, 16, 0, 0);
}

// ---------------------------------------------------------------------------
// K1 prep (unchanged, known-good):
//   blk 0..1023   : x_main  NCHW fp32 -> xT  NHWC f16 (64-px tiles)
//   blk 1024..2047: x_extra NCHW fp32 -> xeF NHWC f16
//   blk 2048..2111: weight repacks spread over 64 blocks
// ---------------------------------------------------------------------------
__global__ __launch_bounds__(256) void k_prep(
    const float* __restrict__ x_main,
    const float* __restrict__ x_extra,
    const float* __restrict__ weight,
    const float* __restrict__ w_om,
    _Float16* __restrict__ xT,
    _Float16* __restrict__ xeF,
    _Float16* __restrict__ Wfrag,
    _Float16* __restrict__ WOMfrag)
{
  const int blk = blockIdx.x;
  const int t = threadIdx.x;

  if (blk < 2048) {
    __shared__ float tile[64 * 65];
    int isExtra = blk >> 10;
    int b  = (blk >> 8) & 3;
    int p0 = (blk & 255) << 6;
    const float* src = (isExtra ? x_extra : x_main) + b * Cn * HWn + p0;
    #pragma unroll
    for (int i = 0; i < 4; ++i) {
      int c  = i * 16 + (t >> 4);
      int p4 = (t & 15) * 4;
      float4 v = *(const float4*)(src + c * HWn + p4);
      tile[c * 65 + p4 + 0] = v.x;    // stride-65: 2-way bank = free
      tile[c * 65 + p4 + 1] = v.y;
      tile[c * 65 + p4 + 2] = v.z;
      tile[c * 65 + p4 + 3] = v.w;
    }
    __syncthreads();
    _Float16* dst = (isExtra ? xeF : xT) + b * XBSTRIDE + p0 * 64;
    int q  = t & 7;
    int pr = t >> 3;
    #pragma unroll
    for (int i = 0; i < 2; ++i) {
      int p = i * 32 + pr;
      v8h pk;
      #pragma unroll
      for (int j = 0; j < 8; ++j)
        pk[j] = (_Float16)tile[(q * 8 + j) * 65 + p];
      *(v8h*)(dst + p * 64 + q * 8) = pk;
    }
  } else {
    int rb = blk - 2048;   // 0..63
    // main-GEMM weights, order (k, hk, ot, ln, j)
    for (int idx = rb * 256 + t; idx < 36864; idx += 64 * 256) {
      int j  = idx & 7;
      int ln = (idx >> 3) & 63;
      int ot = (idx >> 9) & 3;
      int hk = (idx >> 11) & 1;
      int k  = idx >> 12;
      int o = ot * 16 + (ln & 15);
      int c = hk * 32 + (ln >> 4) * 8 + j;
      Wfrag[idx] = (_Float16)weight[(o * Cn + c) * Kn + k];
    }
    // conv weights: order (k9, half, jt, lane, j); j-rows 27..31 zero
    for (int idx = rb * 256 + t; idx < 18432; idx += 64 * 256) {
      int j    = idx & 7;
      int ln   = (idx >> 3) & 63;
      int jt   = (idx >> 9) & 1;
      int half = (idx >> 10) & 1;
      int k9   = idx >> 11;
      int jo = jt * 16 + (ln & 15);
      int c  = half * 32 + (ln >> 4) * 8 + j;
      float v = (jo < 27) ? w_om[(jo * Cn + c) * Kn + k9] : 0.f;
      WOMfrag[idx] = (_Float16)v;
    }
    if (rb == 0 && t < 256) {
      int b = t >> 6, c = t & 63;
      xT[b * XBSTRIDE + ZROW * 64 + c] = (_Float16)0.f;
      xeF[b * XBSTRIDE + ZROW * 64 + c] = (_Float16)0.f;
    }
  }
}

// ---------------------------------------------------------------------------
// K2 fused, o-split for 8 waves/SIMD:
//   2048 blocks (8/CU); adjacent block pair shares (b,h,half), splits o 0..31
//   vs 32..63. Phases 1+2 duplicated per pair (cheap, L2-shared); phase 3
//   halved per wave (acc 2xv4f, 4 A-frags/k). Target VGPR <= 64 (the 8-wave
//   occupancy quantum) -> __launch_bounds__(256, 8). No corner-prefetch
//   pipeline: C/H loaded same-iter, hidden by 2x TLP; publishes use exact
//   uniform vmcnt(0) (all loads same-iter, nothing to preserve).
// LDS (18432B total, <=20KB for 8 blocks/CU):
//   [0,8192)      phase-1 Wom dbuf (2 x 4KB, 1 frag DMA per wave per k9)
//   [0,9216)      jbuf   (overlays dead dbuf after phase-1 + syncthreads)
//   [9216,18432)  recbuf (per-wave, lives through phase 3)
//   [0,8192)      phase-3 Abuf dbuf (2 x 4KB, overlays dead jbuf)
// ---------------------------------------------------------------------------
__global__ __launch_bounds__(256, 8) void k_fused(
    const _Float16* __restrict__ xT,
    const _Float16* __restrict__ xeF,
    const _Float16* __restrict__ Wfrag,
    const _Float16* __restrict__ WOMfrag,
    const float* __restrict__ pre_offset,
    const float* __restrict__ pre_sim,
    const float* __restrict__ b_om,
    const float* __restrict__ bias,
    float* __restrict__ out)
{
  __shared__ __align__(16) char smem[18432];

  const int t    = threadIdx.x;
  const int lane = t & 63;
  const int wv   = __builtin_amdgcn_readfirstlane(t >> 6);
  // XCD swizzle: 2048 blocks, 8 XCDs, 256 contiguous per XCD (bijective).
  // o-half pairs (blk even/odd) land on the SAME XCD -> shared L2 gathers.
  const int raw  = blockIdx.x;
  const int blk  = ((raw & 7) << 8) | (raw >> 3);
  const int oh   = blk & 1;              // o-half: 0 -> o 0..31, 1 -> 32..63
  const int bh   = blk >> 1;             // old (b,h,half) block id
  const int b    = bh >> 8;
  const int h    = (bh >> 1) & 127;
  const int wq   = (bh & 1) * 4 + wv;    // 16-pixel group (0..7)
  const int kq   = lane >> 4;            // c-subgroup / j-subgroup
  const int n    = lane & 15;            // pixel within tile
  const int w    = wq * 16 + n;

  // ---------------- Phase 1: offset conv (Wom 2x4KB dbuf, 1 DMA/wave) -----
  unsigned tapoff[9];
  #pragma unroll
  for (int k9 = 0; k9 < 9; ++k9) {
    int r  = h - 1 + k9 / 3;
    int cc = w - 1 + k9 % 3;
    bool v = ((unsigned)r < (unsigned)Hn) & ((unsigned)cc < (unsigned)Wn);
    tapoff[k9] = (v ? (unsigned)(r * Wn + cc) : (unsigned)ZROW) * 64u;
  }

  const _Float16* xe = xeF + b * XBSTRIDE;
  const v8h* WomV = (const v8h*)WOMfrag;
  v4f ca0 = {0,0,0,0}, ca1 = {0,0,0,0};

  // prologue: each wave DMAs 1 of the 4 k9=0 frags (uniform count)
  gld_lds16(WomV + (0 * 4 + wv) * 64 + lane, smem + wv * 1024);
  __builtin_amdgcn_sched_barrier(0);
  v8h Bt0 = *(const v8h*)(xe + tapoff[0] + kq * 8);
  v8h Bt1 = *(const v8h*)(xe + tapoff[0] + 32 + kq * 8);
  asm volatile("s_waitcnt vmcnt(2)" ::: "memory");   // drain own DMA, keep Bt
  __builtin_amdgcn_s_barrier();                      // k9=0 frags published

  #pragma unroll
  for (int k9 = 0; k9 < 9; ++k9) {
    if (k9 < 8)
      gld_lds16(WomV + ((k9 + 1) * 4 + wv) * 64 + lane,
                smem + ((k9 + 1) & 1) * 4096 + wv * 1024);
    __builtin_amdgcn_sched_barrier(0);
    v8h Bn0, Bn1;
    if (k9 < 8) {
      Bn0 = *(const v8h*)(xe + tapoff[k9 + 1] + kq * 8);
      Bn1 = *(const v8h*)(xe + tapoff[k9 + 1] + 32 + kq * 8);
    }
    __builtin_amdgcn_sched_barrier(0);
    const char* fb = smem + (k9 & 1) * 4096 + lane * 16;
    v8h A00 = *(const v8h*)(fb);
    v8h A01 = *(const v8h*)(fb + 1024);
    ca0 = __builtin_amdgcn_mfma_f32_16x16x32_f16(A00, Bt0, ca0, 0, 0, 0);
    ca1 = __builtin_amdgcn_mfma_f32_16x16x32_f16(A01, Bt0, ca1, 0, 0, 0);
    v8h A10 = *(const v8h*)(fb + 2048);
    v8h A11 = *(const v8h*)(fb + 3072);
    ca0 = __builtin_amdgcn_mfma_f32_16x16x32_f16(A10, Bt1, ca0, 0, 0, 0);
    ca1 = __builtin_amdgcn_mfma_f32_16x16x32_f16(A11, Bt1, ca1, 0, 0, 0);
    if (k9 < 8) {
      Bt0 = Bn0; Bt1 = Bn1;
      asm volatile("s_waitcnt vmcnt(2)" ::: "memory"); // drain DMA, keep Bn
      __builtin_amdgcn_s_barrier();                    // publish next frags
    }
  }
  __syncthreads();   // dbuf dead everywhere -> jbuf overlay safe

  // jbuf overlay [0,9216): D col=lane&15 (pixel), row=kq*4+reg (j)
  float* jb = (float*)smem + wv * 576;
  *(v4f*)(jb + n * 36 + kq * 4)      = ca0;     // j 0..15
  *(v4f*)(jb + n * 36 + 16 + kq * 4) = ca1;     // j 16..31

  // ---------------- Phase 2: gather records (per-wave LDS) -----------------
  uint4* rb = (uint4*)(smem + 9216) + wv * 144;  // 16*9 uint4 per wave
  if (kq < 3) {
    #pragma unroll
    for (int kk = 0; kk < 3; ++kk) {
      int k = kq * 3 + kk;
      float sy = jb[n * 36 + 2 * k]     + b_om[2 * k];
      float sx = jb[n * 36 + 2 * k + 1] + b_om[2 * k + 1];
      float sm = jb[n * 36 + 18 + k]    + b_om[18 + k];
      int pbase = ((b * Kn + k) * Hn + h) * Wn + w;
      float2 po = *(const float2*)(pre_offset + pbase * 2);
      // 10*tanh(s) = 10 - 20/(exp(2s)+1)
      float ey = __expf(2.f * sy);
      float ex = __expf(2.f * sx);
      float py = 10.f - 20.f / (ey + 1.f) + po.y + (float)(h - 1 + k / 3);
      float px = 10.f - 20.f / (ex + 1.f) + po.x + (float)(w - 1 + k % 3);
      float m  = 1.f / (1.f + __expf(-sm * pre_sim[pbase]));
      float fy = floorf(py), fx = floorf(px);
      float dy = py - fy, dx = px - fx;
      int y0 = (int)fy, x0 = (int)fx;
      int y1 = y0 + 1, x1 = x0 + 1;
      bool vy0 = (y0 >= 0) & (y0 < Hn), vy1 = (y1 >= 0) & (y1 < Hn);
      bool vx0 = (x0 >= 0) & (x0 < Wn), vx1 = (x1 >= 0) & (x1 < Wn);
      unsigned r00 = (vy0 & vx0) ? (unsigned)(y0 * Wn + x0) : ZROW;
      unsigned r01 = (vy0 & vx1) ? (unsigned)(y0 * Wn + x1) : ZROW;
      unsigned r10 = (vy1 & vx0) ? (unsigned)(y1 * Wn + x0) : ZROW;
      unsigned r11 = (vy1 & vx1) ? (unsigned)(y1 * Wn + x1) : ZROW;
      float wy0 = 1.f - dy, wx0 = 1.f - dx;
      uint4 rec;
      rec.x = r00 | (r01 << 16);
      rec.y = r10 | (r11 << 16);
      rec.z = (unsigned)f2h(wy0 * wx0 * m) | ((unsigned)f2h(wy0 * dx * m) << 16);
      rec.w = (unsigned)f2h(dy * wx0 * m) | ((unsigned)f2h(dy * dx * m) << 16);
      rb[n * 9 + k] = rec;
    }
  }
  __syncthreads();   // jbuf dead everywhere -> Abuf overlay safe

  // ---------------- Phase 3: main gather-GEMM (o-half, TLP-hidden) --------
  v4f acc0 = {0,0,0,0}, acc1 = {0,0,0,0};
  const _Float16* xb = xT + b * XBSTRIDE;
  const v8h* Wf = (const v8h*)Wfrag;
  // this wave stages frag: wv0->(hk0,j0) wv1->(hk0,j1) wv2->(hk1,j0) wv3->(hk1,j1)
  const int fsel = (wv >> 1) * 4 + 2 * oh + (wv & 1);

  gld_lds16(Wf + (0 * 8 + fsel) * 64 + lane, smem + wv * 1024);
  __builtin_amdgcn_sched_barrier(0);
  uint4 rec_cur = rb[n * 9 + 0];
  asm volatile("s_waitcnt vmcnt(0)" ::: "memory");   // drain DMA
  __builtin_amdgcn_s_barrier();                      // Abuf[0] ready

  #pragma unroll
  for (int k = 0; k < 9; ++k) {
    _Float16 h00 = u2h(rec_cur.z), h01 = u2h(rec_cur.z >> 16);
    _Float16 h10 = u2h(rec_cur.w), h11 = u2h(rec_cur.w >> 16);
    unsigned o00 = (rec_cur.x & 0xffff) * 64u + kq * 8;
    unsigned o01 = (rec_cur.x >> 16)    * 64u + kq * 8;
    unsigned o10 = (rec_cur.y & 0xffff) * 64u + kq * 8;
    unsigned o11 = (rec_cur.y >> 16)    * 64u + kq * 8;
    v8h C0 = *(const v8h*)(xb + o00);
    v8h C1 = *(const v8h*)(xb + o01);
    v8h C2 = *(const v8h*)(xb + o10);
    v8h C3 = *(const v8h*)(xb + o11);
    if (k < 8)
      gld_lds16(Wf + ((k + 1) * 8 + fsel) * 64 + lane,
                smem + ((k + 1) & 1) * 4096 + wv * 1024);
    __builtin_amdgcn_sched_barrier(0);
    uint4 rec_nx = rec_cur;
    if (k < 8) rec_nx = rb[n * 9 + k + 1];

    const char* Ab = smem + (k & 1) * 4096 + lane * 16;
    v8h F0 = *(const v8h*)(Ab);          // (hk0, j0)
    v8h F1 = *(const v8h*)(Ab + 1024);   // (hk0, j1)
    v8h Bf0 = C0 * sp8(h00) + C1 * sp8(h01) + C2 * sp8(h10) + C3 * sp8(h11);
    acc0 = __builtin_amdgcn_mfma_f32_16x16x32_f16(F0, Bf0, acc0, 0, 0, 0);
    acc1 = __builtin_amdgcn_mfma_f32_16x16x32_f16(F1, Bf0, acc1, 0, 0, 0);

    __builtin_amdgcn_sched_barrier(0);   // keep H issue below Bf0 (VGPR peak)
    v8h H0 = *(const v8h*)(xb + o00 + 32);
    v8h H1 = *(const v8h*)(xb + o01 + 32);
    v8h H2 = *(const v8h*)(xb + o10 + 32);
    v8h H3 = *(const v8h*)(xb + o11 + 32);
    v8h F2 = *(const v8h*)(Ab + 2048);   // (hk1, j0)
    v8h F3 = *(const v8h*)(Ab + 3072);   // (hk1, j1)
    v8h Bf1 = H0 * sp8(h00) + H1 * sp8(h01) + H2 * sp8(h10) + H3 * sp8(h11);
    acc0 = __builtin_amdgcn_mfma_f32_16x16x32_f16(F2, Bf1, acc0, 0, 0, 0);
    acc1 = __builtin_amdgcn_mfma_f32_16x16x32_f16(F3, Bf1, acc1, 0, 0, 0);

    rec_cur = rec_nx;
    if (k < 8) {
      // all this iter's loads complete; nothing in flight to preserve
      asm volatile("s_waitcnt vmcnt(0)" ::: "memory");
      __builtin_amdgcn_s_barrier();      // publish Abuf[(k+1)&1]
    }
  }

  // epilogue: D col=lane&15 (pix), row=kq*4+reg; o = oh*32 + j*16 + row
  const float4* b4 = (const float4*)bias;
  float4 vb0 = b4[(oh * 2 + 0) * 4 + kq];
  float4 vb1 = b4[(oh * 2 + 1) * 4 + kq];
  float* ob = out + (b * On + oh * 32) * HWn + h * Wn + wq * 16 + n;
  #pragma unroll
  for (int reg = 0; reg < 4; ++reg) {
    ob[(0 * 16 + kq * 4 + reg) * HWn] = acc0[reg] + ((const float*)&vb0)[reg];
    ob[(1 * 16 + kq * 4 + reg) * HWn] = acc1[reg] + ((const float*)&vb1)[reg];
  }
}

extern "C" void kernel_launch(void* const* d_in, const int* in_sizes, int n_in,
                              void* d_out, int out_size, void* d_ws, size_t ws_size,
                              hipStream_t stream) {
  const float* x_main     = (const float*)d_in[0];
  const float* x_extra    = (const float*)d_in[1];
  const float* pre_offset = (const float*)d_in[2];
  const float* pre_sim    = (const float*)d_in[3];
  const float* weight     = (const float*)d_in[4];
  const float* bias       = (const float*)d_in[5];
  const float* w_om       = (const float*)d_in[6];
  const float* b_om       = (const float*)d_in[7];
  float* out = (float*)d_out;

  char* ws = (char*)d_ws;
  _Float16* xT      = (_Float16*)(ws);              //  8,389,120 B
  _Float16* xeF     = (_Float16*)(ws + 8389120);    //  8,389,120 B
  _Float16* Wfrag   = (_Float16*)(ws + 16778240);   //     73,728 B
  _Float16* WOMfrag = (_Float16*)(ws + 16851968);   //     36,864 B

  k_prep<<<2112, 256, 0, stream>>>(x_main, x_extra, weight, w_om,
                                   xT, xeF, Wfrag, WOMfrag);
  k_fused<<<2048, 256, 0, stream>>>(xT, xeF, Wfrag, WOMfrag,
                                    pre_offset, pre_sim, b_om, bias, out);
}

// Round 10
// 141.887 us; speedup vs baseline: 1.2952x; 1.2952x over previous
//
#include <hip/hip_runtime.h>
#include <math.h>

#define Bn 4
#define Cn 64
#define On 64
#define Hn 128
#define Wn 128
#define Kn 9
#define HWn (Hn*Wn)
#define ZROW 16384            // per-batch zero row index
#define XBSTRIDE (16385*64)   // per-batch stride (16384 rows + 1 zero row)

typedef _Float16 v8h __attribute__((ext_vector_type(8)));
typedef float v4f __attribute__((ext_vector_type(4)));

__device__ inline unsigned short f2h(float f) {
  _Float16 h = (_Float16)f;
  return __builtin_bit_cast(unsigned short, h);
}
__device__ inline _Float16 u2h(unsigned v) {
  return __builtin_bit_cast(_Float16, (unsigned short)(v & 0xffff));
}
__device__ inline v8h sp8(_Float16 x) { v8h v = {x,x,x,x,x,x,x,x}; return v; }

// global -> LDS direct DMA, 16B per lane, LDS dest = uniform base + lane*16
__device__ inline void gld_lds16(const void* g, void* s) {
  __builtin_amdgcn_global_load_lds(
      (const __attribute__((address_space(1))) unsigned int*)g,
      (__attribute__((address_space(3))) unsigned int*)s, 16, 0, 0);
}

// ---------------------------------------------------------------------------
// K1 prep (known-good):
//   blk 0..1023   : x_main  NCHW fp32 -> xT  NHWC f16 (64-px tiles)
//   blk 1024..2047: x_extra NCHW fp32 -> xeF NHWC f16
//   blk 2048..2111: weight repacks spread over 64 blocks
// ---------------------------------------------------------------------------
__global__ __launch_bounds__(256) void k_prep(
    const float* __restrict__ x_main,
    const float* __restrict__ x_extra,
    const float* __restrict__ weight,
    const float* __restrict__ w_om,
    _Float16* __restrict__ xT,
    _Float16* __restrict__ xeF,
    _Float16* __restrict__ Wfrag,
    _Float16* __restrict__ WOMfrag)
{
  const int blk = blockIdx.x;
  const int t = threadIdx.x;

  if (blk < 2048) {
    __shared__ float tile[64 * 65];
    int isExtra = blk >> 10;
    int b  = (blk >> 8) & 3;
    int p0 = (blk & 255) << 6;
    const float* src = (isExtra ? x_extra : x_main) + b * Cn * HWn + p0;
    // float4 coalesced reads: wave covers 4 channel-rows x 256B
    #pragma unroll
    for (int i = 0; i < 4; ++i) {
      int c  = i * 16 + (t >> 4);
      int p4 = (t & 15) * 4;
      float4 v = *(const float4*)(src + c * HWn + p4);
      tile[c * 65 + p4 + 0] = v.x;    // stride-65: 2-way bank = free
      tile[c * 65 + p4 + 1] = v.y;
      tile[c * 65 + p4 + 2] = v.z;
      tile[c * 65 + p4 + 3] = v.w;
    }
    __syncthreads();
    _Float16* dst = (isExtra ? xeF : xT) + b * XBSTRIDE + p0 * 64;
    // v8h stores: lane packs 8 channels; wave stores 1KB contiguous
    int q  = t & 7;          // channel octet
    int pr = t >> 3;         // pixel within half-tile
    #pragma unroll
    for (int i = 0; i < 2; ++i) {
      int p = i * 32 + pr;
      v8h pk;
      #pragma unroll
      for (int j = 0; j < 8; ++j)
        pk[j] = (_Float16)tile[(q * 8 + j) * 65 + p];   // 2-way bank: free
      *(v8h*)(dst + p * 64 + q * 8) = pk;
    }
  } else {
    int rb = blk - 2048;   // 0..63
    // main-GEMM weights, order (k, hk, ot, ln, j):
    // A[o=ot*16+(ln&15)][c=hk*32+(ln>>4)*8+j]
    for (int idx = rb * 256 + t; idx < 36864; idx += 64 * 256) {
      int j  = idx & 7;
      int ln = (idx >> 3) & 63;
      int ot = (idx >> 9) & 3;
      int hk = (idx >> 11) & 1;
      int k  = idx >> 12;
      int o = ot * 16 + (ln & 15);
      int c = hk * 32 + (ln >> 4) * 8 + j;
      Wfrag[idx] = (_Float16)weight[(o * Cn + c) * Kn + k];
    }
    // conv weights: order (k9, half, jt, lane, j); j-rows 27..31 zero
    for (int idx = rb * 256 + t; idx < 18432; idx += 64 * 256) {
      int j    = idx & 7;
      int ln   = (idx >> 3) & 63;
      int jt   = (idx >> 9) & 1;
      int half = (idx >> 10) & 1;
      int k9   = idx >> 11;
      int jo = jt * 16 + (ln & 15);
      int c  = half * 32 + (ln >> 4) * 8 + j;
      float v = (jo < 27) ? w_om[(jo * Cn + c) * Kn + k9] : 0.f;
      WOMfrag[idx] = (_Float16)v;
    }
    if (rb == 0 && t < 256) {
      int b = t >> 6, c = t & 63;
      xT[b * XBSTRIDE + ZROW * 64 + c] = (_Float16)0.f;
      xeF[b * XBSTRIDE + ZROW * 64 + c] = (_Float16)0.f;
    }
  }
}

// ---------------------------------------------------------------------------
// K2 fused (round-7 structure — best measured; restored after the round-9
// o-split experiment refuted the occupancy theory: 2x waves, 2x per-CU work
// -> 1.8x slower. The binder is the per-CU scattered-VMEM request stream;
// this structure minimizes per-CU work (all shareable operands deduped).
//   Phase 1: ENTIRE WOMfrag (36KB == whole smem) DMA'd to LDS once (9 frags
//            per wave, ONE vmcnt+barrier) -> k9 loop fully barrier-free.
//   Phase 2: gather records, per-wave LDS overlay on dead Wom region.
//   Phase 3: A-frags double-buffered via DMA, half1 same-iter (L1-warm),
//            half0 of k+1 prefetched, counted vmcnt(4) publishes.
// LDS overlay (36864B total):
//   [0,36864)    phase-1 Wom frags (9 k9 x 4KB)
//   [0,9216)     jbuf    (over dead Wom k9=0,1)  after post-phase-1 barrier
//   [9216,18432) recbuf  (over dead k9=2,3)
//   [18432,34816) Abuf[2][8KB] (over dead k9=4..7)
// ---------------------------------------------------------------------------
__global__ __launch_bounds__(256, 4) void k_fused(
    const _Float16* __restrict__ xT,
    const _Float16* __restrict__ xeF,
    const _Float16* __restrict__ Wfrag,
    const _Float16* __restrict__ WOMfrag,
    const float* __restrict__ pre_offset,
    const float* __restrict__ pre_sim,
    const float* __restrict__ b_om,
    const float* __restrict__ bias,
    float* __restrict__ out)
{
  __shared__ __align__(16) char smem[36864];

  const int t    = threadIdx.x;
  const int lane = t & 63;
  const int wv   = __builtin_amdgcn_readfirstlane(t >> 6);
  // XCD swizzle: 1024 blocks, 8 XCDs, 128 contiguous per XCD (bijective)
  const int raw  = blockIdx.x;
  const int blk  = ((raw & 7) << 7) | (raw >> 3);
  const int b    = blk >> 8;
  const int h    = (blk >> 1) & 127;
  const int wq   = (blk & 1) * 4 + wv;   // 16-pixel group (0..7)
  const int kq   = lane >> 4;            // c-subgroup / j-subgroup
  const int n    = lane & 15;            // pixel within tile
  const int w    = wq * 16 + n;

  // ---------------- Phase 1: offset conv (barrier-free k-loop) ------------
  unsigned tapoff[9];
  #pragma unroll
  for (int k9 = 0; k9 < 9; ++k9) {
    int r  = h - 1 + k9 / 3;
    int cc = w - 1 + k9 % 3;
    bool v = ((unsigned)r < (unsigned)Hn) & ((unsigned)cc < (unsigned)Wn);
    tapoff[k9] = (v ? (unsigned)(r * Wn + cc) : (unsigned)ZROW) * 64u;
  }

  const _Float16* xe = xeF + b * XBSTRIDE;
  v4f ca0 = {0,0,0,0}, ca1 = {0,0,0,0};

  // DMA the ENTIRE WOMfrag (36 frags x 1KB) into smem: wave wv does 9 frags
  {
    const v8h* WomV = (const v8h*)WOMfrag;
    #pragma unroll
    for (int f = 0; f < 9; ++f) {
      int id = wv * 9 + f;
      gld_lds16(WomV + id * 64 + lane, smem + id * 1024);
    }
  }
  __builtin_amdgcn_sched_barrier(0);
  v8h Bt0 = *(const v8h*)(xe + tapoff[0] + kq * 8);
  v8h Bt1 = *(const v8h*)(xe + tapoff[0] + 32 + kq * 8);
  asm volatile("s_waitcnt vmcnt(2)" ::: "memory");  // drain own 9 DMAs, keep Bt
  __builtin_amdgcn_s_barrier();                     // all 36KB published

  #pragma unroll
  for (int k9 = 0; k9 < 9; ++k9) {
    v8h Bn0, Bn1;
    if (k9 < 8) {
      Bn0 = *(const v8h*)(xe + tapoff[k9 + 1] + kq * 8);
      Bn1 = *(const v8h*)(xe + tapoff[k9 + 1] + 32 + kq * 8);
    }
    __builtin_amdgcn_sched_barrier(0);
    const char* fb = smem + k9 * 4096 + lane * 16;
    v8h A00 = *(const v8h*)(fb);
    v8h A01 = *(const v8h*)(fb + 1024);
    ca0 = __builtin_amdgcn_mfma_f32_16x16x32_f16(A00, Bt0, ca0, 0, 0, 0);
    ca1 = __builtin_amdgcn_mfma_f32_16x16x32_f16(A01, Bt0, ca1, 0, 0, 0);
    v8h A10 = *(const v8h*)(fb + 2048);
    v8h A11 = *(const v8h*)(fb + 3072);
    ca0 = __builtin_amdgcn_mfma_f32_16x16x32_f16(A10, Bt1, ca0, 0, 0, 0);
    ca1 = __builtin_amdgcn_mfma_f32_16x16x32_f16(A11, Bt1, ca1, 0, 0, 0);
    if (k9 < 8) { Bt0 = Bn0; Bt1 = Bn1; }
  }
  __syncthreads();   // Wom region now dead everywhere -> overlays are safe

  // jbuf overlay [0,9216): D col=lane&15 (pixel), row=kq*4+reg (j)
  float* jb = (float*)smem + wv * 576;          // 16*36 floats per wave
  *(v4f*)(jb + n * 36 + kq * 4)      = ca0;     // j 0..15
  *(v4f*)(jb + n * 36 + 16 + kq * 4) = ca1;     // j 16..31

  // phase-3 prologue DMA: wave 0 stages k=0 A-frags (8KB) into Abuf[0];
  // overlaps the phase-2 record math below.
  const v8h* Wf = (const v8h*)Wfrag;
  char* AbufB = smem + 18432;
  if (wv == 0) {
    #pragma unroll
    for (int f = 0; f < 8; ++f)
      gld_lds16(Wf + f * 64 + lane, AbufB + f * 1024);
  }
  __builtin_amdgcn_sched_barrier(0);

  // ---------------- Phase 2: gather records --------------------------------
  uint4* rb = (uint4*)(smem + 9216) + wv * 144;  // 16*9 uint4 per wave
  if (kq < 3) {
    #pragma unroll
    for (int kk = 0; kk < 3; ++kk) {
      int k = kq * 3 + kk;
      float sy = jb[n * 36 + 2 * k]     + b_om[2 * k];
      float sx = jb[n * 36 + 2 * k + 1] + b_om[2 * k + 1];
      float sm = jb[n * 36 + 18 + k]    + b_om[18 + k];
      int pbase = ((b * Kn + k) * Hn + h) * Wn + w;
      float2 po = *(const float2*)(pre_offset + pbase * 2);
      // 10*tanh(s) = 10 - 20/(exp(2s)+1)  (monotone, correct +/-inf limits)
      float ey = __expf(2.f * sy);
      float ex = __expf(2.f * sx);
      float py = 10.f - 20.f / (ey + 1.f) + po.y + (float)(h - 1 + k / 3);
      float px = 10.f - 20.f / (ex + 1.f) + po.x + (float)(w - 1 + k % 3);
      float m  = 1.f / (1.f + __expf(-sm * pre_sim[pbase]));
      float fy = floorf(py), fx = floorf(px);
      float dy = py - fy, dx = px - fx;
      int y0 = (int)fy, x0 = (int)fx;
      int y1 = y0 + 1, x1 = x0 + 1;
      bool vy0 = (y0 >= 0) & (y0 < Hn), vy1 = (y1 >= 0) & (y1 < Hn);
      bool vx0 = (x0 >= 0) & (x0 < Wn), vx1 = (x1 >= 0) & (x1 < Wn);
      unsigned r00 = (vy0 & vx0) ? (unsigned)(y0 * Wn + x0) : ZROW;
      unsigned r01 = (vy0 & vx1) ? (unsigned)(y0 * Wn + x1) : ZROW;
      unsigned r10 = (vy1 & vx0) ? (unsigned)(y1 * Wn + x0) : ZROW;
      unsigned r11 = (vy1 & vx1) ? (unsigned)(y1 * Wn + x1) : ZROW;
      float wy0 = 1.f - dy, wx0 = 1.f - dx;
      uint4 rec;
      rec.x = r00 | (r01 << 16);
      rec.y = r10 | (r11 << 16);
      rec.z = (unsigned)f2h(wy0 * wx0 * m) | ((unsigned)f2h(wy0 * dx * m) << 16);
      rec.w = (unsigned)f2h(dy * wx0 * m) | ((unsigned)f2h(dy * dx * m) << 16);
      rb[n * 9 + k] = rec;
    }
  }

  // ---------------- Phase 3: main gather-GEMM ------------------------------
  v4f acc0 = {0,0,0,0}, acc1 = {0,0,0,0}, acc2 = {0,0,0,0}, acc3 = {0,0,0,0};
  const _Float16* xb = xT + b * XBSTRIDE;

  uint4 rec0   = rb[n * 9 + 0];
  uint4 rec_nx = rb[n * 9 + 1];
  _Float16 h00 = u2h(rec0.z), h01 = u2h(rec0.z >> 16);
  _Float16 h10 = u2h(rec0.w), h11 = u2h(rec0.w >> 16);
  unsigned o00 = (rec0.x & 0xffff) * 64u + kq * 8;
  unsigned o01 = (rec0.x >> 16)    * 64u + kq * 8;
  unsigned o10 = (rec0.y & 0xffff) * 64u + kq * 8;
  unsigned o11 = (rec0.y >> 16)    * 64u + kq * 8;
  v8h C0 = *(const v8h*)(xb + o00);
  v8h C1 = *(const v8h*)(xb + o01);
  v8h C2 = *(const v8h*)(xb + o10);
  v8h C3 = *(const v8h*)(xb + o11);
  // producer (wv0): 8 DMAs oldest + 4 C newest -> vmcnt(4) drains DMAs only.
  asm volatile("s_waitcnt vmcnt(4)" ::: "memory");
  __builtin_amdgcn_s_barrier();                      // publish Abuf[0]

  #pragma unroll
  for (int k = 0; k < 9; ++k) {
    // ------- load block -------
    if (k < 8 && wv == ((k + 1) & 3)) {
      #pragma unroll
      for (int f = 0; f < 8; ++f)
        gld_lds16(Wf + ((k + 1) * 8 + f) * 64 + lane,
                  AbufB + ((k + 1) & 1) * 8192 + f * 1024);
    }
    // half1 of k (same 128B lines as half0 -> L1-warm)
    v8h H0 = *(const v8h*)(xb + o00 + 32);
    v8h H1 = *(const v8h*)(xb + o01 + 32);
    v8h H2 = *(const v8h*)(xb + o10 + 32);
    v8h H3 = *(const v8h*)(xb + o11 + 32);

    // half0 of k+1 (addresses from rec_nx, read one iter ago)
    v8h N0, N1, N2, N3;
    _Float16 nh00 = (_Float16)0.f, nh01 = (_Float16)0.f;
    _Float16 nh10 = (_Float16)0.f, nh11 = (_Float16)0.f;
    unsigned p00 = 0, p01 = 0, p10 = 0, p11 = 0;
    if (k < 8) {
      nh00 = u2h(rec_nx.z); nh01 = u2h(rec_nx.z >> 16);
      nh10 = u2h(rec_nx.w); nh11 = u2h(rec_nx.w >> 16);
      p00 = (rec_nx.x & 0xffff) * 64u + kq * 8;
      p01 = (rec_nx.x >> 16)    * 64u + kq * 8;
      p10 = (rec_nx.y & 0xffff) * 64u + kq * 8;
      p11 = (rec_nx.y >> 16)    * 64u + kq * 8;
      N0 = *(const v8h*)(xb + p00);
      N1 = *(const v8h*)(xb + p01);
      N2 = *(const v8h*)(xb + p10);
      N3 = *(const v8h*)(xb + p11);
    }
    uint4 rec_nx2 = rec_nx;
    if (k < 7) rec_nx2 = rb[n * 9 + k + 2];

    // ------- pin: loads above, compute below -------
    __builtin_amdgcn_sched_barrier(0);

    const char* Ab = AbufB + (k & 1) * 8192 + lane * 16;
    v8h F0 = *(const v8h*)(Ab);
    v8h F1 = *(const v8h*)(Ab + 1024);
    v8h F2 = *(const v8h*)(Ab + 2048);
    v8h F3 = *(const v8h*)(Ab + 3072);

    v8h Bf0 = C0 * sp8(h00) + C1 * sp8(h01) + C2 * sp8(h10) + C3 * sp8(h11);

    acc0 = __builtin_amdgcn_mfma_f32_16x16x32_f16(F0, Bf0, acc0, 0, 0, 0);
    acc1 = __builtin_amdgcn_mfma_f32_16x16x32_f16(F1, Bf0, acc1, 0, 0, 0);
    acc2 = __builtin_amdgcn_mfma_f32_16x16x32_f16(F2, Bf0, acc2, 0, 0, 0);
    acc3 = __builtin_amdgcn_mfma_f32_16x16x32_f16(F3, Bf0, acc3, 0, 0, 0);

    v8h F4 = *(const v8h*)(Ab + 4096);
    v8h F5 = *(const v8h*)(Ab + 5120);
    v8h F6 = *(const v8h*)(Ab + 6144);
    v8h F7 = *(const v8h*)(Ab + 7168);
    v8h Bf1 = H0 * sp8(h00) + H1 * sp8(h01) + H2 * sp8(h10) + H3 * sp8(h11);

    acc0 = __builtin_amdgcn_mfma_f32_16x16x32_f16(F4, Bf1, acc0, 0, 0, 0);
    acc1 = __builtin_amdgcn_mfma_f32_16x16x32_f16(F5, Bf1, acc1, 0, 0, 0);
    acc2 = __builtin_amdgcn_mfma_f32_16x16x32_f16(F6, Bf1, acc2, 0, 0, 0);
    acc3 = __builtin_amdgcn_mfma_f32_16x16x32_f16(F7, Bf1, acc3, 0, 0, 0);

    if (k < 8) {
      C0 = N0; C1 = N1; C2 = N2; C3 = N3;
      h00 = nh00; h01 = nh01; h10 = nh10; h11 = nh11;
      o00 = p00; o01 = p01; o10 = p10; o11 = p11;
      rec_nx = rec_nx2;
      // publish Abuf[(k+1)&1]: drain DMAs (+H), keep the 4 N prefetches
      asm volatile("s_waitcnt vmcnt(4)" ::: "memory");
      __builtin_amdgcn_s_barrier();
    }
  }

  // epilogue: D col=lane&15 (pix), row=kq*4+reg (o within 16-o tile)
  const float4* b4 = (const float4*)bias;
  float4 vb0 = b4[0 * 4 + kq], vb1 = b4[1 * 4 + kq];
  float4 vb2 = b4[2 * 4 + kq], vb3 = b4[3 * 4 + kq];
  float* ob = out + (b * On) * HWn + h * Wn + wq * 16 + n;
  #pragma unroll
  for (int reg = 0; reg < 4; ++reg) {
    ob[(0 * 16 + kq * 4 + reg) * HWn] = acc0[reg] + ((const float*)&vb0)[reg];
    ob[(1 * 16 + kq * 4 + reg) * HWn] = acc1[reg] + ((const float*)&vb1)[reg];
    ob[(2 * 16 + kq * 4 + reg) * HWn] = acc2[reg] + ((const float*)&vb2)[reg];
    ob[(3 * 16 + kq * 4 + reg) * HWn] = acc3[reg] + ((const float*)&vb3)[reg];
  }
}

extern "C" void kernel_launch(void* const* d_in, const int* in_sizes, int n_in,
                              void* d_out, int out_size, void* d_ws, size_t ws_size,
                              hipStream_t stream) {
  const float* x_main     = (const float*)d_in[0];
  const float* x_extra    = (const float*)d_in[1];
  const float* pre_offset = (const float*)d_in[2];
  const float* pre_sim    = (const float*)d_in[3];
  const float* weight     = (const float*)d_in[4];
  const float* bias       = (const float*)d_in[5];
  const float* w_om       = (const float*)d_in[6];
  const float* b_om       = (const float*)d_in[7];
  float* out = (float*)d_out;

  char* ws = (char*)d_ws;
  _Float16* xT      = (_Float16*)(ws);              //  8,389,120 B
  _Float16* xeF     = (_Float16*)(ws + 8389120);    //  8,389,120 B
  _Float16* Wfrag   = (_Float16*)(ws + 16778240);   //     73,728 B
  _Float16* WOMfrag = (_Float16*)(ws + 16851968);   //     36,864 B

  k_prep<<<2112, 256, 0, stream>>>(x_main, x_extra, weight, w_om,
                                   xT, xeF, Wfrag, WOMfrag);
  k_fused<<<1024, 256, 0, stream>>>(xT, xeF, Wfrag, WOMfrag,
                                    pre_offset, pre_sim, b_om, bias, out);
}